// Round 4
// baseline (257.048 us; speedup 1.0000x reference)
//
#include <hip/hip_runtime.h>
#include <hip/hip_bf16.h>
#include <stdint.h>

#define BN 8192
#define DK 256
#define KLOG2E_T 20.609929155556617f    // log2(e)/0.07
#define INV_T 14.285714285714286f       // 1/0.07
#define NEGINF (-3.0e38f)

typedef short vshort8 __attribute__((ext_vector_type(8)));
typedef float vfloat16 __attribute__((ext_vector_type(16)));

__device__ __forceinline__ void gload16(const void* g, void* lds) {
  __builtin_amdgcn_global_load_lds(
      (const __attribute__((address_space(1))) unsigned int*)g,
      (__attribute__((address_space(3))) unsigned int*)lds, 16, 0, 0);
}

// ---------- prep: fp32->bf16, keys, chains, cntA, G partials (one kernel) ----------
__global__ __launch_bounds__(256) void prep_g(
    const float* __restrict__ P, const int* __restrict__ aff,
    const int* __restrict__ inst, ushort* __restrict__ Pb,
    int* __restrict__ keys, int* __restrict__ head, int* __restrict__ nxt,
    int* __restrict__ cntA, float* __restrict__ G) {
  __shared__ float4 Gl[4][16][64];   // 16 KB; (rg,c) thread-private per a
  __shared__ int hist[16];
  const int t = threadIdx.x;
  const int rg = t >> 6, c = t & 63;
  for (int idx = t; idx < 4096; idx += 256)
    ((float4*)Gl)[idx] = make_float4(0.f, 0.f, 0.f, 0.f);
  if (t < 16) hist[t] = 0;
  __syncthreads();
  const int r0 = blockIdx.x * 64;
  for (int k = 0; k < 16; ++k) {
    const int r = r0 + k * 4 + rg;
    float4 v = ((const float4*)(P + (size_t)r * DK))[c];
    ushort4 h;
    __hip_bfloat16 b;
    b = __float2bfloat16(v.x); h.x = __builtin_bit_cast(unsigned short, b);
    b = __float2bfloat16(v.y); h.y = __builtin_bit_cast(unsigned short, b);
    b = __float2bfloat16(v.z); h.z = __builtin_bit_cast(unsigned short, b);
    b = __float2bfloat16(v.w); h.w = __builtin_bit_cast(unsigned short, b);
    ((ushort4*)(Pb + (size_t)r * DK))[c] = h;
    const int a = aff[r];
    float4 g = Gl[rg][a][c];
    g.x += v.x; g.y += v.y; g.z += v.z; g.w += v.w;
    Gl[rg][a][c] = g;
  }
  if (t < 64) {
    const int g = r0 + t;
    const int a = aff[g];
    const int k = (a << 12) | inst[g];
    keys[g] = k;
    nxt[g] = atomicExch(&head[k], g + 1);   // 0 = empty, rows stored +1
    atomicAdd(&hist[a], 1);
  }
  __syncthreads();
  if (t < 16) atomicAdd(&cntA[t], hist[t]);
  for (int idx = t; idx < 1024; idx += 256) {
    const int a = idx >> 6, cc = idx & 63;
    float4 s0 = Gl[0][a][cc], s1 = Gl[1][a][cc];
    float4 s2 = Gl[2][a][cc], s3 = Gl[3][a][cc];
    atomicAdd(&G[a * 256 + cc * 4 + 0], s0.x + s1.x + s2.x + s3.x);
    atomicAdd(&G[a * 256 + cc * 4 + 1], s0.y + s1.y + s2.y + s3.y);
    atomicAdd(&G[a * 256 + cc * 4 + 2], s0.z + s1.z + s2.z + s3.z);
    atomicAdd(&G[a * 256 + cc * 4 + 3], s0.w + s1.w + s2.w + s3.w);
  }
}

// ---------------- fused GEMM (32x32x16) + single-pass LSE partials ----------------
// LDS rows are 64 B (32 bf16). Bank-conflict-free swizzle: 16B-block position
// = blk ^ ((row>>1)&3); combined with the row&1 bank-half this spreads a b128
// fragment read (rows = base+lo) over all 8 16B slots uniformly.
__global__ __launch_bounds__(512, 2) void fused_kernel(
    const ushort* __restrict__ Pb, float2* __restrict__ stats) {
  __shared__ __align__(16) char AbufB[8 * 128 * 64];   // 64KB: [kc][row][64B]
  __shared__ __align__(16) char BbufB[2 * 512 * 64];   // 64KB: [buf][row][64B]
  __shared__ float2 red[8][2][32];                     // 2KB epilogue merge

  const int tid = threadIdx.x;
  const int w = tid >> 6;       // 0..7
  const int l = tid & 63;
  const int lo = l & 31;
  const int hi = l >> 5;
  const int iw = w >> 2;        // 0..1 : 64 i-rows each
  const int jw = w & 3;         // 0..3 : 128 j-cols each

  const int bid = blockIdx.x;
  const int xcd = bid & 7;
  const int local = bid >> 3;                 // 0..127
  const int jc = (xcd << 1) | (local & 1);    // 0..15 (XCD-locked j-chunk)
  const int it = local >> 1;                  // 0..63
  const int ibase = it * 128;
  const int jcbase = jc * 512;

  // staging: thread t -> (row = t>>2, blkpos = t&3); source block pre-swizzled
  const int srow = tid >> 2;                  // 0..127
  const int sswz = ((tid & 3) ^ ((srow >> 1) & 3)) * 16;
  const char* gA = (const char*)(Pb + (size_t)ibase * DK);
  const char* gB = (const char*)(Pb + (size_t)jcbase * DK);

  // ---- prologue: full A (8 k-chunks) + B chunk 0 ----
#pragma unroll
  for (int e = 0; e < 8; ++e)
    gload16(gA + (size_t)srow * 512 + e * 64 + sswz, AbufB + e * 8192 + tid * 16);
#pragma unroll
  for (int e = 0; e < 4; ++e)
    gload16(gB + (size_t)(e * 128 + srow) * 512 + sswz,
            BbufB + e * 8192 + tid * 16);
  __syncthreads();

  // per-lane fragment read offsets; gblk = kk*2+hi, pos = gblk ^ ((lo>>1)&3)
  const int rowa = iw * 64 + lo;
  const int rowb = jw * 128 + lo;
  const int rsw = (lo >> 1) & 3;
  const int sw0 = ((0 + hi) ^ rsw) * 16;
  const int sw1 = ((2 + hi) ^ rsw) * 16;

  vfloat16 acc[2][4];
#pragma unroll
  for (int mi = 0; mi < 2; ++mi)
#pragma unroll
    for (int nj = 0; nj < 4; ++nj)
#pragma unroll
      for (int r = 0; r < 16; ++r) acc[mi][nj][r] = 0.f;

  for (int kc = 0; kc < 8; ++kc) {
    if (kc < 7) {  // prefetch next B chunk into other buffer
      char* dst = BbufB + ((kc + 1) & 1) * 32768 + tid * 16;
      const char* src = gB + (size_t)srow * 512 + (kc + 1) * 64 + sswz;
#pragma unroll
      for (int e = 0; e < 4; ++e)
        gload16(src + (size_t)e * 128 * 512, dst + e * 8192);
    }
    const char* As = AbufB + kc * 8192;
    const char* Bs = BbufB + (kc & 1) * 32768;
#pragma unroll
    for (int kk = 0; kk < 2; ++kk) {
      const int so = kk ? sw1 : sw0;
      vshort8 a0 = *(const vshort8*)(As + rowa * 64 + so);
      vshort8 a1 = *(const vshort8*)(As + (rowa + 32) * 64 + so);
#pragma unroll
      for (int nj = 0; nj < 4; ++nj) {
        vshort8 jf = *(const vshort8*)(Bs + (rowb + nj * 32) * 64 + so);
        acc[0][nj] = __builtin_amdgcn_mfma_f32_32x32x16_bf16(jf, a0, acc[0][nj], 0, 0, 0);
        acc[1][nj] = __builtin_amdgcn_mfma_f32_32x32x16_bf16(jf, a1, acc[1][nj], 0, 0, 0);
      }
    }
    __syncthreads();
  }

  // ---- epilogue (once per block): self-mask, max, exp-sum ----
  float mx[2] = {NEGINF, NEGINF};
#pragma unroll
  for (int mi = 0; mi < 2; ++mi) {
    const int gib = ibase + iw * 64 + mi * 32;
#pragma unroll
    for (int nj = 0; nj < 4; ++nj) {
      const bool dia = gib == (jcbase + jw * 128 + nj * 32);
      if (dia) {
#pragma unroll
        for (int r = 0; r < 16; ++r) {
          const int jj = (r & 3) + 8 * (r >> 2) + 4 * hi;
          if (jj == lo) acc[mi][nj][r] = NEGINF;
        }
      }
#pragma unroll
      for (int r = 0; r < 16; ++r) mx[mi] = fmaxf(mx[mi], acc[mi][nj][r]);
    }
  }
  mx[0] = fmaxf(mx[0], __shfl_xor(mx[0], 32));
  mx[1] = fmaxf(mx[1], __shfl_xor(mx[1], 32));
  float s[2] = {0.f, 0.f};
#pragma unroll
  for (int mi = 0; mi < 2; ++mi) {
    const float rc = -mx[mi] * KLOG2E_T;
#pragma unroll
    for (int nj = 0; nj < 4; ++nj)
#pragma unroll
      for (int r = 0; r < 16; ++r)
        s[mi] += exp2f(fmaf(acc[mi][nj][r], KLOG2E_T, rc));
  }
  s[0] += __shfl_xor(s[0], 32);
  s[1] += __shfl_xor(s[1], 32);
  if (l < 32) {
    red[w][0][lo] = make_float2(mx[0], s[0]);
    red[w][1][lo] = make_float2(mx[1], s[1]);
  }
  __syncthreads();
  if (tid < 128) {  // merge the 4 j-waves per row
    const int iw2 = tid >> 6, mi2 = (tid >> 5) & 1, lo2 = tid & 31;
    float2 a = red[iw2 * 4 + 0][mi2][lo2];
    float mm = a.x, ss = a.y;
#pragma unroll
    for (int j2 = 1; j2 < 4; ++j2) {
      float2 b = red[iw2 * 4 + j2][mi2][lo2];
      float M = fmaxf(mm, b.x);
      ss = ss * exp2f((mm - M) * KLOG2E_T) + b.y * exp2f((b.x - M) * KLOG2E_T);
      mm = M;
    }
    stats[(size_t)jc * BN + ibase + iw2 * 64 + mi2 * 32 + lo2] = make_float2(mm, ss);
  }
}

// -------- per-row: merge 16 lse-partials + algebraic pos-sums + finalize --------
__global__ __launch_bounds__(256) void final_rows(
    const float2* __restrict__ stats, const float* __restrict__ P,
    const float* __restrict__ G, const int* __restrict__ keys,
    const int* __restrict__ head, const int* __restrict__ nxt,
    const int* __restrict__ cntA, float* __restrict__ accum,
    int* __restrict__ done, float* __restrict__ out) {
  const int t = threadIdx.x;
  const int rloc = t >> 6;    // 0..3
  const int lane = t & 63;
  const int i = blockIdx.x * 4 + rloc;

  // merge 16 (m,s) partials via shuffle tree (lanes replicated x4)
  float2 st = stats[(size_t)(lane & 15) * BN + i];
  float mm = st.x, ss = st.y;
#pragma unroll
  for (int off = 1; off < 16; off <<= 1) {
    float mo = __shfl_xor(mm, off);
    float so = __shfl_xor(ss, off);
    float M = fmaxf(mm, mo);
    ss = ss * exp2f((mm - M) * KLOG2E_T) + so * exp2f((mo - M) * KLOG2E_T);
    mm = M;
  }
  const float lse = logf(ss) + mm * INV_T;

  // Sum_pos sim = (P_i . G[a] - Sum_{key==} P_i . P_j) / T   (exact fp32)
  const int key = keys[i];
  const int a = key >> 12;
  float4 p4 = ((const float4*)(P + (size_t)i * 256))[lane];
  float4 g4 = ((const float4*)(G + a * 256))[lane];
  float acc = p4.x * g4.x + p4.y * g4.y + p4.z * g4.z + p4.w * g4.w;
  int cnt = 0;
  int j = head[key];
  while (j > 0) {                        // same-key rows (includes self), +1 enc
    const int jr = j - 1;
    float4 q4 = ((const float4*)(P + (size_t)jr * 256))[lane];
    acc -= p4.x * q4.x + p4.y * q4.y + p4.z * q4.z + p4.w * q4.w;
    cnt++;
    j = nxt[jr];
  }
#pragma unroll
  for (int off = 1; off < 64; off <<= 1) acc += __shfl_xor(acc, off);
  const float pc = (float)(cntA[a] - cnt);
  const float contrib = pc * lse - acc * INV_T;

  __shared__ float cs[4], ps[4];
  if (lane == 0) { cs[rloc] = contrib; ps[rloc] = pc; }
  __syncthreads();
  if (t == 0) {
    atomicAdd(&accum[0], cs[0] + cs[1] + cs[2] + cs[3]);
    atomicAdd(&accum[1], ps[0] + ps[1] + ps[2] + ps[3]);
    __threadfence();
    if (atomicAdd(done, 1) == (int)gridDim.x - 1) {
      const float c = atomicAdd(&accum[0], 0.f);
      const float p = atomicAdd(&accum[1], 0.f);
      out[0] = (p > 0.f) ? (c / p) : 0.f;
    }
  }
}

extern "C" void kernel_launch(void* const* d_in, const int* in_sizes, int n_in,
                              void* d_out, int out_size, void* d_ws, size_t ws_size,
                              hipStream_t stream) {
  const float* P = (const float*)d_in[0];
  const int* aff = (const int*)d_in[1];
  const int* inst = (const int*)d_in[2];
  char* ws = (char*)d_ws;
  ushort* Pb    = (ushort*)(ws);                      // 4 MB
  int*    keys  = (int*)(ws + 4194304);               // 32 KB
  int*    nxt   = (int*)(ws + 4227072);               // 32 KB
  // --- zero region (one memset): head | G | cntA | accum | done ---
  int*    head  = (int*)(ws + 4259840);               // 256 KB (65536 bins)
  float*  G     = (float*)(ws + 4521984);             // 16 KB (16x256)
  int*    cntA  = (int*)(ws + 4538368);               // 64 B
  float*  accum = (float*)(ws + 4538432);             // 8 B
  int*    done  = (int*)(ws + 4538440);               // 4 B
  float2* stats = (float2*)(ws + 4538496);            // 1 MB (16 x 8192 x 8B)
  float* out = (float*)d_out;

  hipMemsetAsync(head, 0, 278656, stream);            // head..done = 0
  prep_g<<<128, 256, 0, stream>>>(P, aff, inst, Pb, keys, head, nxt, cntA, G);
  fused_kernel<<<1024, 512, 0, stream>>>(Pb, stats);
  final_rows<<<2048, 256, 0, stream>>>(stats, P, G, keys, head, nxt, cntA,
                                       accum, done, out);
}

// Round 5
// 91.984 us; speedup vs baseline: 2.7945x; 2.7945x over previous
//
#include <hip/hip_runtime.h>
#include <hip/hip_bf16.h>
#include <stdint.h>

#define BN 8192
#define DK 256
#define KLOG2E_T 20.609929155556617f    // log2(e)/0.07
#define INV_T 14.285714285714286f       // 1/0.07
#define NEGINF (-3.0e38f)

typedef short vshort8 __attribute__((ext_vector_type(8)));
typedef float vfloat16 __attribute__((ext_vector_type(16)));

__device__ __forceinline__ void gload16(const void* g, void* lds) {
  __builtin_amdgcn_global_load_lds(
      (const __attribute__((address_space(1))) unsigned int*)g,
      (__attribute__((address_space(3))) unsigned int*)lds, 16, 0, 0);
}

// ---------- prep: fp32->bf16, keys, chains, cntA, G partials (one kernel) ----------
__global__ __launch_bounds__(256) void prep_g(
    const float* __restrict__ P, const int* __restrict__ aff,
    const int* __restrict__ inst, ushort* __restrict__ Pb,
    int* __restrict__ keys, int* __restrict__ head, int* __restrict__ nxt,
    int* __restrict__ cntA, float* __restrict__ G) {
  __shared__ float4 Gl[4][16][64];   // 16 KB; (rg,c) thread-private per a
  __shared__ int hist[16];
  const int t = threadIdx.x;
  const int rg = t >> 6, c = t & 63;
  for (int idx = t; idx < 4096; idx += 256)
    ((float4*)Gl)[idx] = make_float4(0.f, 0.f, 0.f, 0.f);
  if (t < 16) hist[t] = 0;
  __syncthreads();
  const int r0 = blockIdx.x * 64;
  for (int k = 0; k < 16; ++k) {
    const int r = r0 + k * 4 + rg;
    float4 v = ((const float4*)(P + (size_t)r * DK))[c];
    ushort4 h;
    __hip_bfloat16 b;
    b = __float2bfloat16(v.x); h.x = __builtin_bit_cast(unsigned short, b);
    b = __float2bfloat16(v.y); h.y = __builtin_bit_cast(unsigned short, b);
    b = __float2bfloat16(v.z); h.z = __builtin_bit_cast(unsigned short, b);
    b = __float2bfloat16(v.w); h.w = __builtin_bit_cast(unsigned short, b);
    ((ushort4*)(Pb + (size_t)r * DK))[c] = h;
    const int a = aff[r];
    float4 g = Gl[rg][a][c];
    g.x += v.x; g.y += v.y; g.z += v.z; g.w += v.w;
    Gl[rg][a][c] = g;
  }
  if (t < 64) {
    const int g = r0 + t;
    const int a = aff[g];
    const int k = (a << 12) | inst[g];
    keys[g] = k;
    nxt[g] = atomicExch(&head[k], g + 1);   // 0 = empty, rows stored +1
    atomicAdd(&hist[a], 1);
  }
  __syncthreads();
  if (t < 16) atomicAdd(&cntA[t], hist[t]);
  for (int idx = t; idx < 1024; idx += 256) {
    const int a = idx >> 6, cc = idx & 63;
    float4 s0 = Gl[0][a][cc], s1 = Gl[1][a][cc];
    float4 s2 = Gl[2][a][cc], s3 = Gl[3][a][cc];
    atomicAdd(&G[a * 256 + cc * 4 + 0], s0.x + s1.x + s2.x + s3.x);
    atomicAdd(&G[a * 256 + cc * 4 + 1], s0.y + s1.y + s2.y + s3.y);
    atomicAdd(&G[a * 256 + cc * 4 + 2], s0.z + s1.z + s2.z + s3.z);
    atomicAdd(&G[a * 256 + cc * 4 + 3], s0.w + s1.w + s2.w + s3.w);
  }
}

// ---------------- fused GEMM (32x32x16) + single-pass LSE partials ----------------
// LDS rows are 64 B (32 bf16). Bank-conflict-free swizzle: 16B-block position
// = blk ^ ((row>>1)&3); combined with the row&1 bank-half this spreads a b128
// fragment read (rows = base+lo) over all 8 16B slots uniformly.
__global__ __launch_bounds__(512, 2) void fused_kernel(
    const ushort* __restrict__ Pb, float2* __restrict__ stats) {
  __shared__ __align__(16) char AbufB[8 * 128 * 64];   // 64KB: [kc][row][64B]
  __shared__ __align__(16) char BbufB[2 * 512 * 64];   // 64KB: [buf][row][64B]
  __shared__ float2 red[8][2][32];                     // 2KB epilogue merge

  const int tid = threadIdx.x;
  const int w = tid >> 6;       // 0..7
  const int l = tid & 63;
  const int lo = l & 31;
  const int hi = l >> 5;
  const int iw = w >> 2;        // 0..1 : 64 i-rows each
  const int jw = w & 3;         // 0..3 : 128 j-cols each

  const int bid = blockIdx.x;
  const int xcd = bid & 7;
  const int local = bid >> 3;                 // 0..127
  const int jc = (xcd << 1) | (local & 1);    // 0..15 (XCD-locked j-chunk)
  const int it = local >> 1;                  // 0..63
  const int ibase = it * 128;
  const int jcbase = jc * 512;

  // staging: thread t -> (row = t>>2, blkpos = t&3); source block pre-swizzled
  const int srow = tid >> 2;                  // 0..127
  const int sswz = ((tid & 3) ^ ((srow >> 1) & 3)) * 16;
  const char* gA = (const char*)(Pb + (size_t)ibase * DK);
  const char* gB = (const char*)(Pb + (size_t)jcbase * DK);

  // ---- prologue: full A (8 k-chunks) + B chunk 0 ----
#pragma unroll
  for (int e = 0; e < 8; ++e)
    gload16(gA + (size_t)srow * 512 + e * 64 + sswz, AbufB + e * 8192 + tid * 16);
#pragma unroll
  for (int e = 0; e < 4; ++e)
    gload16(gB + (size_t)(e * 128 + srow) * 512 + sswz,
            BbufB + e * 8192 + tid * 16);
  __syncthreads();

  // per-lane fragment read offsets; gblk = kk*2+hi, pos = gblk ^ ((lo>>1)&3)
  const int rowa = iw * 64 + lo;
  const int rowb = jw * 128 + lo;
  const int rsw = (lo >> 1) & 3;
  const int sw0 = ((0 + hi) ^ rsw) * 16;
  const int sw1 = ((2 + hi) ^ rsw) * 16;

  vfloat16 acc[2][4];
#pragma unroll
  for (int mi = 0; mi < 2; ++mi)
#pragma unroll
    for (int nj = 0; nj < 4; ++nj)
#pragma unroll
      for (int r = 0; r < 16; ++r) acc[mi][nj][r] = 0.f;

  for (int kc = 0; kc < 8; ++kc) {
    if (kc < 7) {  // prefetch next B chunk into other buffer
      char* dst = BbufB + ((kc + 1) & 1) * 32768 + tid * 16;
      const char* src = gB + (size_t)srow * 512 + (kc + 1) * 64 + sswz;
#pragma unroll
      for (int e = 0; e < 4; ++e)
        gload16(src + (size_t)e * 128 * 512, dst + e * 8192);
    }
    const char* As = AbufB + kc * 8192;
    const char* Bs = BbufB + (kc & 1) * 32768;
#pragma unroll
    for (int kk = 0; kk < 2; ++kk) {
      const int so = kk ? sw1 : sw0;
      vshort8 a0 = *(const vshort8*)(As + rowa * 64 + so);
      vshort8 a1 = *(const vshort8*)(As + (rowa + 32) * 64 + so);
#pragma unroll
      for (int nj = 0; nj < 4; ++nj) {
        vshort8 jf = *(const vshort8*)(Bs + (rowb + nj * 32) * 64 + so);
        acc[0][nj] = __builtin_amdgcn_mfma_f32_32x32x16_bf16(jf, a0, acc[0][nj], 0, 0, 0);
        acc[1][nj] = __builtin_amdgcn_mfma_f32_32x32x16_bf16(jf, a1, acc[1][nj], 0, 0, 0);
      }
    }
    __syncthreads();
  }

  // ---- epilogue (once per block): self-mask, max, exp-sum ----
  float mx[2] = {NEGINF, NEGINF};
#pragma unroll
  for (int mi = 0; mi < 2; ++mi) {
    const int gib = ibase + iw * 64 + mi * 32;
#pragma unroll
    for (int nj = 0; nj < 4; ++nj) {
      const bool dia = gib == (jcbase + jw * 128 + nj * 32);
      if (dia) {
#pragma unroll
        for (int r = 0; r < 16; ++r) {
          const int jj = (r & 3) + 8 * (r >> 2) + 4 * hi;
          if (jj == lo) acc[mi][nj][r] = NEGINF;
        }
      }
#pragma unroll
      for (int r = 0; r < 16; ++r) mx[mi] = fmaxf(mx[mi], acc[mi][nj][r]);
    }
  }
  mx[0] = fmaxf(mx[0], __shfl_xor(mx[0], 32));
  mx[1] = fmaxf(mx[1], __shfl_xor(mx[1], 32));
  float s[2] = {0.f, 0.f};
#pragma unroll
  for (int mi = 0; mi < 2; ++mi) {
    const float rc = -mx[mi] * KLOG2E_T;
#pragma unroll
    for (int nj = 0; nj < 4; ++nj)
#pragma unroll
      for (int r = 0; r < 16; ++r)
        s[mi] += exp2f(fmaf(acc[mi][nj][r], KLOG2E_T, rc));
  }
  s[0] += __shfl_xor(s[0], 32);
  s[1] += __shfl_xor(s[1], 32);
  if (l < 32) {
    red[w][0][lo] = make_float2(mx[0], s[0]);
    red[w][1][lo] = make_float2(mx[1], s[1]);
  }
  __syncthreads();
  if (tid < 128) {  // merge the 4 j-waves per row
    const int iw2 = tid >> 6, mi2 = (tid >> 5) & 1, lo2 = tid & 31;
    float2 a = red[iw2 * 4 + 0][mi2][lo2];
    float mm = a.x, ss = a.y;
#pragma unroll
    for (int j2 = 1; j2 < 4; ++j2) {
      float2 b = red[iw2 * 4 + j2][mi2][lo2];
      float M = fmaxf(mm, b.x);
      ss = ss * exp2f((mm - M) * KLOG2E_T) + b.y * exp2f((b.x - M) * KLOG2E_T);
      mm = M;
    }
    stats[(size_t)jc * BN + ibase + iw2 * 64 + mi2 * 32 + lo2] = make_float2(mm, ss);
  }
}

// -------- per-row: merge 16 lse-partials + algebraic pos-sums --------
__global__ __launch_bounds__(256) void final_rows(
    const float2* __restrict__ stats, const float* __restrict__ P,
    const float* __restrict__ G, const int* __restrict__ keys,
    const int* __restrict__ head, const int* __restrict__ nxt,
    const int* __restrict__ cntA, float2* __restrict__ part) {
  const int t = threadIdx.x;
  const int rloc = t >> 6;    // 0..3
  const int lane = t & 63;
  const int i = blockIdx.x * 4 + rloc;

  // merge 16 (m,s) partials via shuffle tree (lanes replicated x4)
  float2 st = stats[(size_t)(lane & 15) * BN + i];
  float mm = st.x, ss = st.y;
#pragma unroll
  for (int off = 1; off < 16; off <<= 1) {
    float mo = __shfl_xor(mm, off);
    float so = __shfl_xor(ss, off);
    float M = fmaxf(mm, mo);
    ss = ss * exp2f((mm - M) * KLOG2E_T) + so * exp2f((mo - M) * KLOG2E_T);
    mm = M;
  }
  const float lse = logf(ss) + mm * INV_T;

  // Sum_pos sim = (P_i . G[a] - Sum_{key==} P_i . P_j) / T   (exact fp32)
  const int key = keys[i];
  const int a = key >> 12;
  float4 p4 = ((const float4*)(P + (size_t)i * 256))[lane];
  float4 g4 = ((const float4*)(G + a * 256))[lane];
  float acc = p4.x * g4.x + p4.y * g4.y + p4.z * g4.z + p4.w * g4.w;
  int cnt = 0;
  int j = head[key];
  while (j > 0) {                        // same-key rows (includes self), +1 enc
    const int jr = j - 1;
    float4 q4 = ((const float4*)(P + (size_t)jr * 256))[lane];
    acc -= p4.x * q4.x + p4.y * q4.y + p4.z * q4.z + p4.w * q4.w;
    cnt++;
    j = nxt[jr];
  }
#pragma unroll
  for (int off = 1; off < 64; off <<= 1) acc += __shfl_xor(acc, off);
  const float pc = (float)(cntA[a] - cnt);
  const float contrib = pc * lse - acc * INV_T;

  __shared__ float cs[4], ps[4];
  if (lane == 0) { cs[rloc] = contrib; ps[rloc] = pc; }
  __syncthreads();
  if (t == 0)
    part[blockIdx.x] = make_float2(cs[0] + cs[1] + cs[2] + cs[3],
                                   ps[0] + ps[1] + ps[2] + ps[3]);
}

__global__ void finalize(const float2* __restrict__ part, float* __restrict__ out) {
  const int t = threadIdx.x;   // 256 threads
  float c = 0.f, p = 0.f;
  for (int k = t; k < 2048; k += 256) {
    float2 v = part[k];
    c += v.x;
    p += v.y;
  }
#pragma unroll
  for (int off = 1; off < 64; off <<= 1) {
    c += __shfl_xor(c, off);
    p += __shfl_xor(p, off);
  }
  __shared__ float cs[4], ps[4];
  if ((t & 63) == 0) { cs[t >> 6] = c; ps[t >> 6] = p; }
  __syncthreads();
  if (t == 0) {
    c = cs[0] + cs[1] + cs[2] + cs[3];
    p = ps[0] + ps[1] + ps[2] + ps[3];
    out[0] = (p > 0.f) ? (c / p) : 0.f;
  }
}

extern "C" void kernel_launch(void* const* d_in, const int* in_sizes, int n_in,
                              void* d_out, int out_size, void* d_ws, size_t ws_size,
                              hipStream_t stream) {
  const float* P = (const float*)d_in[0];
  const int* aff = (const int*)d_in[1];
  const int* inst = (const int*)d_in[2];
  char* ws = (char*)d_ws;
  ushort* Pb    = (ushort*)(ws);                      // 4 MB
  int*    keys  = (int*)(ws + 4194304);               // 32 KB
  int*    nxt   = (int*)(ws + 4227072);               // 32 KB
  // --- zero region (one memset): head | G | cntA ---
  int*    head  = (int*)(ws + 4259840);               // 256 KB (65536 bins)
  float*  G     = (float*)(ws + 4521984);             // 16 KB (16x256)
  int*    cntA  = (int*)(ws + 4538368);               // 64 B
  float2* stats = (float2*)(ws + 4538496);            // 1 MB (16 x 8192 x 8B)
  float2* part  = (float2*)(ws + 5587072);            // 16 KB
  float* out = (float*)d_out;

  hipMemsetAsync(head, 0, 278592, stream);            // head..cntA = 0
  prep_g<<<128, 256, 0, stream>>>(P, aff, inst, Pb, keys, head, nxt, cntA, G);
  fused_kernel<<<1024, 512, 0, stream>>>(Pb, stats);
  final_rows<<<2048, 256, 0, stream>>>(stats, P, G, keys, head, nxt, cntA, part);
  finalize<<<1, 256, 0, stream>>>(part, out);
}